// Round 4
// baseline (897.745 us; speedup 1.0000x reference)
//
#include <hip/hip_runtime.h>
#include <math.h>

#define D_MODEL 1024
#define N_HEADS 16
#define D_HEAD  64
#define LSR_RANK 32
#define BATCH 2
#define SEQ 2048
#define M_TOT (BATCH*SEQ)          // 4096 rows (B*T)
#define NCAT  2048                 // q_lr(512) | k_lr(512) | v(1024)

// ---------------------------------------------------------------------------
// Weff[k, h*32+r] = sum_d W[k, h*64+d] * Wlsr[h, d, r]
// ---------------------------------------------------------------------------
__global__ __launch_bounds__(256) void eff_weight_kernel(
    const float* __restrict__ W, const float* __restrict__ Wlsr,
    float* __restrict__ Weff)
{
    int idx = blockIdx.x * 256 + threadIdx.x;     // 1024*512 outputs
    int k = idx >> 9;
    int c = idx & 511;
    int h = c >> 5;
    int r = c & 31;
    const float* wrow = W + (size_t)k * D_MODEL + h * D_HEAD;
    const float* lsr  = Wlsr + (size_t)h * D_HEAD * LSR_RANK + r;
    float acc = 0.f;
    #pragma unroll
    for (int d = 0; d < D_HEAD; ++d)
        acc = fmaf(wrow[d], lsr[d * LSR_RANK], acc);
    Weff[(size_t)k * (N_HEADS * LSR_RANK) + c] = acc;
}

__global__ void eff_bias_kernel(const float* __restrict__ bias,
                                const float* __restrict__ Wlsr,
                                float* __restrict__ beff)
{
    int c = threadIdx.x;   // 512
    int h = c >> 5, r = c & 31;
    float acc = 0.f;
    #pragma unroll
    for (int d = 0; d < D_HEAD; ++d)
        acc = fmaf(bias[h * D_HEAD + d],
                   Wlsr[(size_t)h * D_HEAD * LSR_RANK + d * LSR_RANK + r], acc);
    beff[c] = acc;
}

// ---------------------------------------------------------------------------
// fp32 GEMM tile: 64 (M) x 128 (N), BK=16, 256 threads, 4x8 micro-tile.
// ---------------------------------------------------------------------------
__device__ __forceinline__ void gemm_tile_64x128(
    const float* __restrict__ A, int lda,
    const float* __restrict__ B, int ldb,
    const float* __restrict__ bias,
    float* __restrict__ C, int ldc)
{
    __shared__ float As[16][68];
    __shared__ float Bs[16][136];

    const int tid = threadIdx.x;
    const int tx = tid & 15;
    const int ty = tid >> 4;
    const int arow = tid >> 2;
    const int akq  = tid & 3;
    const int bn4  = tid & 31;
    const int bk   = tid >> 5;

    float acc[4][8];
    #pragma unroll
    for (int i = 0; i < 4; ++i)
        #pragma unroll
        for (int j = 0; j < 8; ++j) acc[i][j] = 0.f;

    for (int k0 = 0; k0 < D_MODEL; k0 += 16) {
        float4 av = *(const float4*)&A[(size_t)arow * lda + k0 + akq * 4];
        As[akq*4+0][arow] = av.x;
        As[akq*4+1][arow] = av.y;
        As[akq*4+2][arow] = av.z;
        As[akq*4+3][arow] = av.w;
        #pragma unroll
        for (int p = 0; p < 2; ++p) {
            int k = bk + p * 8;
            *(float4*)&Bs[k][bn4 * 4] =
                *(const float4*)&B[(size_t)(k0 + k) * ldb + bn4 * 4];
        }
        __syncthreads();
        #pragma unroll
        for (int kk = 0; kk < 16; ++kk) {
            float4 a  = *(const float4*)&As[kk][ty * 4];
            float4 b0 = *(const float4*)&Bs[kk][tx * 8];
            float4 b1 = *(const float4*)&Bs[kk][tx * 8 + 4];
            float avv[4] = {a.x, a.y, a.z, a.w};
            float bvv[8] = {b0.x, b0.y, b0.z, b0.w, b1.x, b1.y, b1.z, b1.w};
            #pragma unroll
            for (int i = 0; i < 4; ++i)
                #pragma unroll
                for (int j = 0; j < 8; ++j)
                    acc[i][j] = fmaf(avv[i], bvv[j], acc[i][j]);
        }
        __syncthreads();
    }
    #pragma unroll
    for (int i = 0; i < 4; ++i) {
        #pragma unroll
        for (int j = 0; j < 8; ++j) {
            C[(size_t)(ty * 4 + i) * ldc + tx * 8 + j] =
                acc[i][j] + bias[tx * 8 + j];
        }
    }
}

__global__ __launch_bounds__(256) void proj_kernel(
    const float* __restrict__ x,
    const float* __restrict__ Wq_eff, const float* __restrict__ Wk_eff,
    const float* __restrict__ Wv,
    const float* __restrict__ bq_eff, const float* __restrict__ bk_eff,
    const float* __restrict__ bv,
    float* __restrict__ Y)
{
    int n0 = blockIdx.x * 128;
    int m0 = blockIdx.y * 64;
    const float* B; const float* bias; int ldb;
    if (n0 < 512)       { B = Wq_eff + n0;          bias = bq_eff + n0;          ldb = 512;  }
    else if (n0 < 1024) { B = Wk_eff + (n0 - 512);  bias = bk_eff + (n0 - 512);  ldb = 512;  }
    else                { B = Wv + (n0 - 1024);     bias = bv + (n0 - 1024);     ldb = 1024; }
    gemm_tile_64x128(x + (size_t)m0 * D_MODEL, D_MODEL, B, ldb, bias,
                     Y + (size_t)m0 * NCAT + n0, NCAT);
}

__global__ __launch_bounds__(256) void out_kernel(
    const float* __restrict__ O, const float* __restrict__ Wo,
    const float* __restrict__ bo, float* __restrict__ out)
{
    int n0 = blockIdx.x * 128;
    int m0 = blockIdx.y * 64;
    gemm_tile_64x128(O + (size_t)m0 * D_MODEL, D_MODEL, Wo + n0, D_MODEL,
                     bo + n0, out + (size_t)m0 * D_MODEL + n0, D_MODEL);
}

// ---------------------------------------------------------------------------
// Flash attention, v2: 512 threads (8 waves) per block for occupancy.
// blockIdx.x = b*H+h (32), blockIdx.y = q-tile pair (16): q-tiles qt and
// 31-qt (33 kv-tiles total -> uniform load). Thread (row = tid&63,
// oct = tid>>6): oct handles kv columns [8*oct, 8*oct+8) of every kv tile.
// All LDS reads in the hot loops are wave-uniform float4 broadcasts.
// 2 blocks/CU co-resident (LDS ~30 KB, VGPR capped at 128) -> 16 waves/CU.
// ---------------------------------------------------------------------------
#define SK_LD 36
#define SV_LD 68
#define MASKVAL (-1e30f)

__global__ __launch_bounds__(512, 4) void flash_kernel(
    const float* __restrict__ Y,   // (4096, 2048): q_lr | k_lr | v
    float* __restrict__ O)         // (4096, 1024): (B,T,H,Dh)
{
    const float scale = 0.1767766952966369f;  // 1/sqrt(32)
    const int bh = blockIdx.x;
    const int pq = blockIdx.y;                 // 0..15
    const int b = bh >> 4, h = bh & 15;
    const int tid = threadIdx.x;
    const int row = tid & 63;
    const int oct = tid >> 6;                  // 0..7

    __shared__ float smem[64 * SK_LD + 64 * SV_LD];  // sk | sv; reused as accum
    __shared__ float sml[2][8][64];                  // m, l per (oct,row)
    float* sk = smem;                 // [64][SK_LD]
    float* sv = smem + 64 * SK_LD;    // [64][SV_LD]
    float* accum = smem;              // [64][65] after main loop

    #pragma unroll 1
    for (int pass = 0; pass < 2; ++pass) {
        const int qt = pass ? (31 - pq) : pq;
        const int t = qt * 64 + row;

        // load q_lr row into registers
        float q[32];
        {
            const float* qrow = Y + (size_t)(b * SEQ + t) * NCAT + h * 32;
            #pragma unroll
            for (int r4 = 0; r4 < 8; ++r4) {
                float4 f = ((const float4*)qrow)[r4];
                q[r4*4+0] = f.x; q[r4*4+1] = f.y; q[r4*4+2] = f.z; q[r4*4+3] = f.w;
            }
        }
        float o[64];
        #pragma unroll
        for (int d = 0; d < 64; ++d) o[d] = 0.f;
        float mrun = MASKVAL, lrun = 0.f;

        for (int jt = 0; jt <= qt; ++jt) {
            // cooperative tile load: 512 threads, 64 kv rows, 8 loaders/row
            {
                const int r  = tid >> 3;
                const int sg = tid & 7;
                const size_t rb = (size_t)(b * SEQ + jt * 64 + r) * NCAT;
                const float* krow = Y + rb + 512 + h * 32;
                const float* vrow = Y + rb + 1024 + h * 64;
                *(float4*)&sk[r * SK_LD + sg * 4] = ((const float4*)krow)[sg];
                #pragma unroll
                for (int p = 0; p < 2; ++p)
                    *(float4*)&sv[r * SV_LD + sg * 8 + p * 4] =
                        ((const float4*)vrow)[sg * 2 + p];
            }
            __syncthreads();

            // scores for this oct's 8 kv columns (float4 broadcast reads)
            float s[8];
            float mt = MASKVAL;
            #pragma unroll
            for (int jj = 0; jj < 8; ++jj) {
                const int j = oct * 8 + jj;
                const float4* kr = (const float4*)&sk[j * SK_LD];
                float acc = 0.f;
                #pragma unroll
                for (int r4 = 0; r4 < 8; ++r4) {
                    float4 kv = kr[r4];
                    acc = fmaf(q[r4*4+0], kv.x, acc);
                    acc = fmaf(q[r4*4+1], kv.y, acc);
                    acc = fmaf(q[r4*4+2], kv.z, acc);
                    acc = fmaf(q[r4*4+3], kv.w, acc);
                }
                acc *= scale;
                const int gj = jt * 64 + j;
                acc = (gj <= t) ? acc : MASKVAL;
                s[jj] = acc;
                mt = fmaxf(mt, acc);
            }
            const float mnew = fmaxf(mrun, mt);
            const float alpha = expf(mrun - mnew);
            float psum = 0.f;
            #pragma unroll
            for (int jj = 0; jj < 8; ++jj) {
                float p = expf(s[jj] - mnew);
                s[jj] = p;
                psum += p;
            }
            lrun = lrun * alpha + psum;
            #pragma unroll
            for (int d = 0; d < 64; ++d) o[d] *= alpha;
            #pragma unroll
            for (int jj = 0; jj < 8; ++jj) {
                const int j = oct * 8 + jj;
                const float p = s[jj];
                const float4* vr = (const float4*)&sv[j * SV_LD];
                #pragma unroll
                for (int d4 = 0; d4 < 16; ++d4) {
                    float4 vv = vr[d4];
                    o[d4*4+0] = fmaf(p, vv.x, o[d4*4+0]);
                    o[d4*4+1] = fmaf(p, vv.y, o[d4*4+1]);
                    o[d4*4+2] = fmaf(p, vv.z, o[d4*4+2]);
                    o[d4*4+3] = fmaf(p, vv.w, o[d4*4+3]);
                }
            }
            mrun = mnew;
            __syncthreads();
        }

        // combine the 8 oct-partials of each row
        sml[0][oct][row] = mrun;
        sml[1][oct][row] = lrun;
        __syncthreads();
        float mg = MASKVAL;
        #pragma unroll
        for (int qq = 0; qq < 8; ++qq) mg = fmaxf(mg, sml[0][qq][row]);
        float lg = 0.f;
        #pragma unroll
        for (int qq = 0; qq < 8; ++qq)
            lg += sml[1][qq][row] * expf(sml[0][qq][row] - mg);
        const float alpha = expf(mrun - mg);   // 0 for never-valid octs

        // accumulate alpha*o into accum[64][65]; disjoint 8-float ranges/step
        #pragma unroll
        for (int st = 0; st < 8; ++st) {
            const int dr = ((oct + st) & 7) * 8;
            if (st == 0) {
                #pragma unroll
                for (int dd = 0; dd < 8; ++dd)
                    accum[row * 65 + dr + dd] = alpha * o[dr + dd];
            } else {
                #pragma unroll
                for (int dd = 0; dd < 8; ++dd)
                    accum[row * 65 + dr + dd] += alpha * o[dr + dd];
            }
            __syncthreads();
        }

        // write output: thread (row, oct) writes 8 contiguous floats
        {
            const float inv = 1.f / lg;
            float* orow = O + (size_t)(b * SEQ + t) * D_MODEL + h * D_HEAD;
            #pragma unroll
            for (int dd = 0; dd < 8; ++dd)
                orow[oct * 8 + dd] =
                    accum[row * 65 + oct * 8 + dd] * inv;
        }
        __syncthreads();   // smem reused by next pass
    }
}

// ---------------------------------------------------------------------------
extern "C" void kernel_launch(void* const* d_in, const int* in_sizes, int n_in,
                              void* d_out, int out_size, void* d_ws, size_t ws_size,
                              hipStream_t stream)
{
    const float* x      = (const float*)d_in[0];
    const float* Wq     = (const float*)d_in[1];
    const float* bq     = (const float*)d_in[2];
    const float* Wk     = (const float*)d_in[3];
    const float* bk     = (const float*)d_in[4];
    const float* Wv     = (const float*)d_in[5];
    const float* bv     = (const float*)d_in[6];
    const float* Wo     = (const float*)d_in[7];
    const float* bo     = (const float*)d_in[8];
    const float* Wq_lsr = (const float*)d_in[9];
    const float* Wk_lsr = (const float*)d_in[10];
    float* out = (float*)d_out;

    float* ws      = (float*)d_ws;
    float* Wq_eff  = ws;                               // 1024*512
    float* Wk_eff  = Wq_eff + 1024 * 512;              // 1024*512
    float* bq_eff  = Wk_eff + 1024 * 512;              // 512
    float* bk_eff  = bq_eff + 512;                     // 512
    float* Ycat    = bk_eff + 512;                     // 4096*2048
    float* Oacc    = Ycat + (size_t)M_TOT * NCAT;      // 4096*1024

    eff_weight_kernel<<<2048, 256, 0, stream>>>(Wq, Wq_lsr, Wq_eff);
    eff_weight_kernel<<<2048, 256, 0, stream>>>(Wk, Wk_lsr, Wk_eff);
    eff_bias_kernel<<<1, 512, 0, stream>>>(bq, Wq_lsr, bq_eff);
    eff_bias_kernel<<<1, 512, 0, stream>>>(bk, Wk_lsr, bk_eff);

    proj_kernel<<<dim3(NCAT / 128, M_TOT / 64), 256, 0, stream>>>(
        x, Wq_eff, Wk_eff, Wv, bq_eff, bk_eff, bv, Ycat);

    flash_kernel<<<dim3(BATCH * N_HEADS, 16), 512, 0, stream>>>(Ycat, Oacc);

    out_kernel<<<dim3(D_MODEL / 128, M_TOT / 64), 256, 0, stream>>>(
        Oacc, Wo, bo, out);
}

// Round 5
// 883.266 us; speedup vs baseline: 1.0164x; 1.0164x over previous
//
#include <hip/hip_runtime.h>
#include <math.h>

#define D_MODEL 1024
#define N_HEADS 16
#define D_HEAD  64
#define LSR_RANK 32
#define BATCH 2
#define SEQ 2048
#define M_TOT (BATCH*SEQ)          // 4096 rows (B*T)
#define NCAT  2048                 // q_lr(512) | k_lr(512) | v(1024)

// ---------------------------------------------------------------------------
// Weff[k, h*32+r] = sum_d W[k, h*64+d] * Wlsr[h, d, r]
// ---------------------------------------------------------------------------
__global__ __launch_bounds__(256) void eff_weight_kernel(
    const float* __restrict__ W, const float* __restrict__ Wlsr,
    float* __restrict__ Weff)
{
    int idx = blockIdx.x * 256 + threadIdx.x;     // 1024*512 outputs
    int k = idx >> 9;
    int c = idx & 511;
    int h = c >> 5;
    int r = c & 31;
    const float* wrow = W + (size_t)k * D_MODEL + h * D_HEAD;
    const float* lsr  = Wlsr + (size_t)h * D_HEAD * LSR_RANK + r;
    float acc = 0.f;
    #pragma unroll
    for (int d = 0; d < D_HEAD; ++d)
        acc = fmaf(wrow[d], lsr[d * LSR_RANK], acc);
    Weff[(size_t)k * (N_HEADS * LSR_RANK) + c] = acc;
}

__global__ void eff_bias_kernel(const float* __restrict__ bias,
                                const float* __restrict__ Wlsr,
                                float* __restrict__ beff)
{
    int c = threadIdx.x;   // 512
    int h = c >> 5, r = c & 31;
    float acc = 0.f;
    #pragma unroll
    for (int d = 0; d < D_HEAD; ++d)
        acc = fmaf(bias[h * D_HEAD + d],
                   Wlsr[(size_t)h * D_HEAD * LSR_RANK + d * LSR_RANK + r], acc);
    beff[c] = acc;
}

// ---------------------------------------------------------------------------
// fp32 GEMM tile: 64 (M) x 128 (N), BK=16, 256 threads, 4x8 micro-tile.
// ---------------------------------------------------------------------------
__device__ __forceinline__ void gemm_tile_64x128(
    const float* __restrict__ A, int lda,
    const float* __restrict__ B, int ldb,
    const float* __restrict__ bias,
    float* __restrict__ C, int ldc)
{
    __shared__ float As[16][68];
    __shared__ float Bs[16][136];

    const int tid = threadIdx.x;
    const int tx = tid & 15;
    const int ty = tid >> 4;
    const int arow = tid >> 2;
    const int akq  = tid & 3;
    const int bn4  = tid & 31;
    const int bk   = tid >> 5;

    float acc[4][8];
    #pragma unroll
    for (int i = 0; i < 4; ++i)
        #pragma unroll
        for (int j = 0; j < 8; ++j) acc[i][j] = 0.f;

    for (int k0 = 0; k0 < D_MODEL; k0 += 16) {
        float4 av = *(const float4*)&A[(size_t)arow * lda + k0 + akq * 4];
        As[akq*4+0][arow] = av.x;
        As[akq*4+1][arow] = av.y;
        As[akq*4+2][arow] = av.z;
        As[akq*4+3][arow] = av.w;
        #pragma unroll
        for (int p = 0; p < 2; ++p) {
            int k = bk + p * 8;
            *(float4*)&Bs[k][bn4 * 4] =
                *(const float4*)&B[(size_t)(k0 + k) * ldb + bn4 * 4];
        }
        __syncthreads();
        #pragma unroll
        for (int kk = 0; kk < 16; ++kk) {
            float4 a  = *(const float4*)&As[kk][ty * 4];
            float4 b0 = *(const float4*)&Bs[kk][tx * 8];
            float4 b1 = *(const float4*)&Bs[kk][tx * 8 + 4];
            float avv[4] = {a.x, a.y, a.z, a.w};
            float bvv[8] = {b0.x, b0.y, b0.z, b0.w, b1.x, b1.y, b1.z, b1.w};
            #pragma unroll
            for (int i = 0; i < 4; ++i)
                #pragma unroll
                for (int j = 0; j < 8; ++j)
                    acc[i][j] = fmaf(avv[i], bvv[j], acc[i][j]);
        }
        __syncthreads();
    }
    #pragma unroll
    for (int i = 0; i < 4; ++i) {
        #pragma unroll
        for (int j = 0; j < 8; ++j) {
            C[(size_t)(ty * 4 + i) * ldc + tx * 8 + j] =
                acc[i][j] + bias[tx * 8 + j];
        }
    }
}

__global__ __launch_bounds__(256) void proj_kernel(
    const float* __restrict__ x,
    const float* __restrict__ Wq_eff, const float* __restrict__ Wk_eff,
    const float* __restrict__ Wv,
    const float* __restrict__ bq_eff, const float* __restrict__ bk_eff,
    const float* __restrict__ bv,
    float* __restrict__ Y)
{
    int n0 = blockIdx.x * 128;
    int m0 = blockIdx.y * 64;
    const float* B; const float* bias; int ldb;
    if (n0 < 512)       { B = Wq_eff + n0;          bias = bq_eff + n0;          ldb = 512;  }
    else if (n0 < 1024) { B = Wk_eff + (n0 - 512);  bias = bk_eff + (n0 - 512);  ldb = 512;  }
    else                { B = Wv + (n0 - 1024);     bias = bv + (n0 - 1024);     ldb = 1024; }
    gemm_tile_64x128(x + (size_t)m0 * D_MODEL, D_MODEL, B, ldb, bias,
                     Y + (size_t)m0 * NCAT + n0, NCAT);
}

__global__ __launch_bounds__(256) void out_kernel(
    const float* __restrict__ O, const float* __restrict__ Wo,
    const float* __restrict__ bo, float* __restrict__ out)
{
    int n0 = blockIdx.x * 128;
    int m0 = blockIdx.y * 64;
    gemm_tile_64x128(O + (size_t)m0 * D_MODEL, D_MODEL, Wo + n0, D_MODEL,
                     bo + n0, out + (size_t)m0 * D_MODEL + n0, D_MODEL);
}

// ---------------------------------------------------------------------------
// Flash attention, v3: 256 threads (4 waves), NO spills.
//  - __launch_bounds__(256, 2): VGPR ceiling 256 so q[32]+o[64]+s[16] stays
//    in registers (round-4's (512,4) forced VGPR=64 -> o[] spilled to scratch
//    -> 2.5 GB of HBM spill traffic; that was the regression).
//  - grid 32 x 32: one q-tile per block, qt = 31 - blockIdx.y so the big
//    causal tiles dispatch first (LPT balance), 1024 blocks for occupancy.
//  - thread (row = tid&63, quarter = tid>>6) owns 16 kv columns per tile;
//    all hot-loop LDS reads are wave-uniform float4 broadcasts.
// ---------------------------------------------------------------------------
#define SK_LD 36
#define SV_LD 68
#define MASKVAL (-1e30f)

__global__ __launch_bounds__(256, 2) void flash_kernel(
    const float* __restrict__ Y,   // (4096, 2048): q_lr | k_lr | v
    float* __restrict__ O)         // (4096, 1024): (B,T,H,Dh)
{
    const float scale = 0.1767766952966369f;  // 1/sqrt(32)
    const int bh = blockIdx.x;
    const int qt = 31 - blockIdx.y;            // big tiles first
    const int b = bh >> 4, h = bh & 15;
    const int tid = threadIdx.x;
    const int row = tid & 63;
    const int quarter = tid >> 6;              // 0..3, owns 16 kv cols

    __shared__ float smem[64 * SK_LD + 64 * SV_LD];  // sk | sv; reused as accum
    __shared__ float sml[2][4][64];                  // m, l per (quarter,row)
    float* sk = smem;                 // [64][SK_LD]
    float* sv = smem + 64 * SK_LD;    // [64][SV_LD]
    float* accum = smem;              // [64][65] after main loop

    const int t = qt * 64 + row;

    // load q_lr row into registers
    float q[32];
    {
        const float* qrow = Y + (size_t)(b * SEQ + t) * NCAT + h * 32;
        #pragma unroll
        for (int r4 = 0; r4 < 8; ++r4) {
            float4 f = ((const float4*)qrow)[r4];
            q[r4*4+0] = f.x; q[r4*4+1] = f.y; q[r4*4+2] = f.z; q[r4*4+3] = f.w;
        }
    }
    float o[64];
    #pragma unroll
    for (int d = 0; d < 64; ++d) o[d] = 0.f;
    float mrun = MASKVAL, lrun = 0.f;

    for (int jt = 0; jt <= qt; ++jt) {
        // cooperative tile load: 256 threads, 64 kv rows, 4 loaders/row
        {
            const int r  = tid >> 2;
            const int sg = tid & 3;
            const size_t rb = (size_t)(b * SEQ + jt * 64 + r) * NCAT;
            const float* krow = Y + rb + 512 + h * 32;
            const float* vrow = Y + rb + 1024 + h * 64;
            *(float4*)&sk[r * SK_LD + sg * 8]     = ((const float4*)krow)[sg*2];
            *(float4*)&sk[r * SK_LD + sg * 8 + 4] = ((const float4*)krow)[sg*2+1];
            #pragma unroll
            for (int p = 0; p < 4; ++p)
                *(float4*)&sv[r * SV_LD + sg * 16 + p * 4] =
                    ((const float4*)vrow)[sg * 4 + p];
        }
        __syncthreads();

        // scores for this quarter's 16 kv columns (float4 broadcast reads)
        float s[16];
        float mt = MASKVAL;
        #pragma unroll
        for (int jj = 0; jj < 16; ++jj) {
            const int j = quarter * 16 + jj;
            const float4* kr = (const float4*)&sk[j * SK_LD];
            float acc = 0.f;
            #pragma unroll
            for (int r4 = 0; r4 < 8; ++r4) {
                float4 kv = kr[r4];
                acc = fmaf(q[r4*4+0], kv.x, acc);
                acc = fmaf(q[r4*4+1], kv.y, acc);
                acc = fmaf(q[r4*4+2], kv.z, acc);
                acc = fmaf(q[r4*4+3], kv.w, acc);
            }
            acc *= scale;
            const int gj = jt * 64 + j;
            acc = (gj <= t) ? acc : MASKVAL;
            s[jj] = acc;
            mt = fmaxf(mt, acc);
        }
        const float mnew = fmaxf(mrun, mt);
        const float alpha = expf(mrun - mnew);
        float psum = 0.f;
        #pragma unroll
        for (int jj = 0; jj < 16; ++jj) {
            float p = expf(s[jj] - mnew);
            s[jj] = p;
            psum += p;
        }
        lrun = lrun * alpha + psum;
        #pragma unroll
        for (int d = 0; d < 64; ++d) o[d] *= alpha;
        #pragma unroll
        for (int jj = 0; jj < 16; ++jj) {
            const int j = quarter * 16 + jj;
            const float p = s[jj];
            const float4* vr = (const float4*)&sv[j * SV_LD];
            #pragma unroll
            for (int d4 = 0; d4 < 16; ++d4) {
                float4 vv = vr[d4];
                o[d4*4+0] = fmaf(p, vv.x, o[d4*4+0]);
                o[d4*4+1] = fmaf(p, vv.y, o[d4*4+1]);
                o[d4*4+2] = fmaf(p, vv.z, o[d4*4+2]);
                o[d4*4+3] = fmaf(p, vv.w, o[d4*4+3]);
            }
        }
        mrun = mnew;
        __syncthreads();
    }

    // combine the 4 quarter-partials of each row
    sml[0][quarter][row] = mrun;
    sml[1][quarter][row] = lrun;
    __syncthreads();
    float mg = MASKVAL;
    #pragma unroll
    for (int qq = 0; qq < 4; ++qq) mg = fmaxf(mg, sml[0][qq][row]);
    float lg = 0.f;
    #pragma unroll
    for (int qq = 0; qq < 4; ++qq)
        lg += sml[1][qq][row] * expf(sml[0][qq][row] - mg);
    const float alpha = expf(mrun - mg);   // 0 for never-valid quarters

    // accumulate alpha*o into accum[64][65]; disjoint 16-float ranges per step
    #pragma unroll
    for (int st = 0; st < 4; ++st) {
        const int dr = ((quarter + st) & 3) * 16;
        if (st == 0) {
            #pragma unroll
            for (int dd = 0; dd < 16; ++dd)
                accum[row * 65 + dr + dd] = alpha * o[dr + dd];
        } else {
            #pragma unroll
            for (int dd = 0; dd < 16; ++dd)
                accum[row * 65 + dr + dd] += alpha * o[dr + dd];
        }
        __syncthreads();
    }

    // write output: thread (row, quarter) writes 16 contiguous floats
    {
        const float inv = 1.f / lg;
        float* orow = O + (size_t)(b * SEQ + t) * D_MODEL + h * D_HEAD;
        #pragma unroll
        for (int dd = 0; dd < 16; ++dd)
            orow[quarter * 16 + dd] =
                accum[row * 65 + quarter * 16 + dd] * inv;
    }
}

// ---------------------------------------------------------------------------
extern "C" void kernel_launch(void* const* d_in, const int* in_sizes, int n_in,
                              void* d_out, int out_size, void* d_ws, size_t ws_size,
                              hipStream_t stream)
{
    const float* x      = (const float*)d_in[0];
    const float* Wq     = (const float*)d_in[1];
    const float* bq     = (const float*)d_in[2];
    const float* Wk     = (const float*)d_in[3];
    const float* bk     = (const float*)d_in[4];
    const float* Wv     = (const float*)d_in[5];
    const float* bv     = (const float*)d_in[6];
    const float* Wo     = (const float*)d_in[7];
    const float* bo     = (const float*)d_in[8];
    const float* Wq_lsr = (const float*)d_in[9];
    const float* Wk_lsr = (const float*)d_in[10];
    float* out = (float*)d_out;

    float* ws      = (float*)d_ws;
    float* Wq_eff  = ws;                               // 1024*512
    float* Wk_eff  = Wq_eff + 1024 * 512;              // 1024*512
    float* bq_eff  = Wk_eff + 1024 * 512;              // 512
    float* bk_eff  = bq_eff + 512;                     // 512
    float* Ycat    = bk_eff + 512;                     // 4096*2048
    float* Oacc    = Ycat + (size_t)M_TOT * NCAT;      // 4096*1024

    eff_weight_kernel<<<2048, 256, 0, stream>>>(Wq, Wq_lsr, Wq_eff);
    eff_weight_kernel<<<2048, 256, 0, stream>>>(Wk, Wk_lsr, Wk_eff);
    eff_bias_kernel<<<1, 512, 0, stream>>>(bq, Wq_lsr, bq_eff);
    eff_bias_kernel<<<1, 512, 0, stream>>>(bk, Wk_lsr, bk_eff);

    proj_kernel<<<dim3(NCAT / 128, M_TOT / 64), 256, 0, stream>>>(
        x, Wq_eff, Wk_eff, Wv, bq_eff, bk_eff, bv, Ycat);

    flash_kernel<<<dim3(BATCH * N_HEADS, 32), 256, 0, stream>>>(Ycat, Oacc);

    out_kernel<<<dim3(D_MODEL / 128, M_TOT / 64), 256, 0, stream>>>(
        Oacc, Wo, bo, out);
}

// Round 6
// 652.343 us; speedup vs baseline: 1.3762x; 1.3540x over previous
//
#include <hip/hip_runtime.h>
#include <math.h>

#define D_MODEL 1024
#define N_HEADS 16
#define D_HEAD  64
#define LSR_RANK 32
#define BATCH 2
#define SEQ 2048
#define M_TOT (BATCH*SEQ)          // 4096 rows (B*T)
#define NCAT  2048                 // q_lr(512) | k_lr(512) | v(1024)

// ---------------------------------------------------------------------------
// Weff[k, h*32+r] = sum_d W[k, h*64+d] * Wlsr[h, d, r]
// ---------------------------------------------------------------------------
__global__ __launch_bounds__(256) void eff_weight_kernel(
    const float* __restrict__ W, const float* __restrict__ Wlsr,
    float* __restrict__ Weff)
{
    int idx = blockIdx.x * 256 + threadIdx.x;     // 1024*512 outputs
    int k = idx >> 9;
    int c = idx & 511;
    int h = c >> 5;
    int r = c & 31;
    const float* wrow = W + (size_t)k * D_MODEL + h * D_HEAD;
    const float* lsr  = Wlsr + (size_t)h * D_HEAD * LSR_RANK + r;
    float acc = 0.f;
    #pragma unroll
    for (int d = 0; d < D_HEAD; ++d)
        acc = fmaf(wrow[d], lsr[d * LSR_RANK], acc);
    Weff[(size_t)k * (N_HEADS * LSR_RANK) + c] = acc;
}

__global__ void eff_bias_kernel(const float* __restrict__ bias,
                                const float* __restrict__ Wlsr,
                                float* __restrict__ beff)
{
    int c = threadIdx.x;   // 512
    int h = c >> 5, r = c & 31;
    float acc = 0.f;
    #pragma unroll
    for (int d = 0; d < D_HEAD; ++d)
        acc = fmaf(bias[h * D_HEAD + d],
                   Wlsr[(size_t)h * D_HEAD * LSR_RANK + d * LSR_RANK + r], acc);
    beff[c] = acc;
}

// ---------------------------------------------------------------------------
// fp32 GEMM tile: 64 (M) x 128 (N), BK=16, 256 threads, 4x8 micro-tile.
// ---------------------------------------------------------------------------
__device__ __forceinline__ void gemm_tile_64x128(
    const float* __restrict__ A, int lda,
    const float* __restrict__ B, int ldb,
    const float* __restrict__ bias,
    float* __restrict__ C, int ldc)
{
    __shared__ float As[16][68];
    __shared__ float Bs[16][136];

    const int tid = threadIdx.x;
    const int tx = tid & 15;
    const int ty = tid >> 4;
    const int arow = tid >> 2;
    const int akq  = tid & 3;
    const int bn4  = tid & 31;
    const int bk   = tid >> 5;

    float acc[4][8];
    #pragma unroll
    for (int i = 0; i < 4; ++i)
        #pragma unroll
        for (int j = 0; j < 8; ++j) acc[i][j] = 0.f;

    for (int k0 = 0; k0 < D_MODEL; k0 += 16) {
        float4 av = *(const float4*)&A[(size_t)arow * lda + k0 + akq * 4];
        As[akq*4+0][arow] = av.x;
        As[akq*4+1][arow] = av.y;
        As[akq*4+2][arow] = av.z;
        As[akq*4+3][arow] = av.w;
        #pragma unroll
        for (int p = 0; p < 2; ++p) {
            int k = bk + p * 8;
            *(float4*)&Bs[k][bn4 * 4] =
                *(const float4*)&B[(size_t)(k0 + k) * ldb + bn4 * 4];
        }
        __syncthreads();
        #pragma unroll
        for (int kk = 0; kk < 16; ++kk) {
            float4 a  = *(const float4*)&As[kk][ty * 4];
            float4 b0 = *(const float4*)&Bs[kk][tx * 8];
            float4 b1 = *(const float4*)&Bs[kk][tx * 8 + 4];
            float avv[4] = {a.x, a.y, a.z, a.w};
            float bvv[8] = {b0.x, b0.y, b0.z, b0.w, b1.x, b1.y, b1.z, b1.w};
            #pragma unroll
            for (int i = 0; i < 4; ++i)
                #pragma unroll
                for (int j = 0; j < 8; ++j)
                    acc[i][j] = fmaf(avv[i], bvv[j], acc[i][j]);
        }
        __syncthreads();
    }
    #pragma unroll
    for (int i = 0; i < 4; ++i) {
        #pragma unroll
        for (int j = 0; j < 8; ++j) {
            C[(size_t)(ty * 4 + i) * ldc + tx * 8 + j] =
                acc[i][j] + bias[tx * 8 + j];
        }
    }
}

__global__ __launch_bounds__(256) void proj_kernel(
    const float* __restrict__ x,
    const float* __restrict__ Wq_eff, const float* __restrict__ Wk_eff,
    const float* __restrict__ Wv,
    const float* __restrict__ bq_eff, const float* __restrict__ bk_eff,
    const float* __restrict__ bv,
    float* __restrict__ Y)
{
    int n0 = blockIdx.x * 128;
    int m0 = blockIdx.y * 64;
    const float* B; const float* bias; int ldb;
    if (n0 < 512)       { B = Wq_eff + n0;          bias = bq_eff + n0;          ldb = 512;  }
    else if (n0 < 1024) { B = Wk_eff + (n0 - 512);  bias = bk_eff + (n0 - 512);  ldb = 512;  }
    else                { B = Wv + (n0 - 1024);     bias = bv + (n0 - 1024);     ldb = 1024; }
    gemm_tile_64x128(x + (size_t)m0 * D_MODEL, D_MODEL, B, ldb, bias,
                     Y + (size_t)m0 * NCAT + n0, NCAT);
}

__global__ __launch_bounds__(256) void out_kernel(
    const float* __restrict__ O, const float* __restrict__ Wo,
    const float* __restrict__ bo, float* __restrict__ out)
{
    int n0 = blockIdx.x * 128;
    int m0 = blockIdx.y * 64;
    gemm_tile_64x128(O + (size_t)m0 * D_MODEL, D_MODEL, Wo + n0, D_MODEL,
                     bo + n0, out + (size_t)m0 * D_MODEL + n0, D_MODEL);
}

// ---------------------------------------------------------------------------
// Flash attention, v4: v3 + compile-time-indexed o[] epilogue.
// Round-5 diagnosis: the combine epilogue indexed o[dr+dd] with runtime dr
// (= f(quarter)) -> the compiler demoted ALL of o[64] to scratch (VGPR=92,
// 1.1 GB spill writes, main loop scratch-bound). Fix: wave-serialized
// combine -- `quarter == st` is wave-uniform and every o[] access below is
// a literal index, so o[] register-allocates.
// ---------------------------------------------------------------------------
#define SK_LD 36
#define SV_LD 68
#define MASKVAL (-1e30f)

__global__ __launch_bounds__(256, 2) void flash_kernel(
    const float* __restrict__ Y,   // (4096, 2048): q_lr | k_lr | v
    float* __restrict__ O)         // (4096, 1024): (B,T,H,Dh)
{
    const float scale = 0.1767766952966369f;  // 1/sqrt(32)
    const int bh = blockIdx.x;
    const int qt = 31 - blockIdx.y;            // big tiles first (LPT)
    const int b = bh >> 4, h = bh & 15;
    const int tid = threadIdx.x;
    const int row = tid & 63;
    const int quarter = tid >> 6;              // 0..3 == wave id

    __shared__ float smem[64 * SK_LD + 64 * SV_LD];  // sk | sv; reused as accum
    __shared__ float sml[2][4][64];                  // m, l per (quarter,row)
    float* sk = smem;                 // [64][SK_LD]
    float* sv = smem + 64 * SK_LD;    // [64][SV_LD]
    float* accum = smem;              // [64][65] after main loop

    const int t = qt * 64 + row;

    // load q_lr row into registers
    float q[32];
    {
        const float* qrow = Y + (size_t)(b * SEQ + t) * NCAT + h * 32;
        #pragma unroll
        for (int r4 = 0; r4 < 8; ++r4) {
            float4 f = ((const float4*)qrow)[r4];
            q[r4*4+0] = f.x; q[r4*4+1] = f.y; q[r4*4+2] = f.z; q[r4*4+3] = f.w;
        }
    }
    float o[64];
    #pragma unroll
    for (int d = 0; d < 64; ++d) o[d] = 0.f;
    float mrun = MASKVAL, lrun = 0.f;

    for (int jt = 0; jt <= qt; ++jt) {
        // cooperative tile load: 256 threads, 64 kv rows, 4 loaders/row
        {
            const int r  = tid >> 2;
            const int sg = tid & 3;
            const size_t rb = (size_t)(b * SEQ + jt * 64 + r) * NCAT;
            const float* krow = Y + rb + 512 + h * 32;
            const float* vrow = Y + rb + 1024 + h * 64;
            *(float4*)&sk[r * SK_LD + sg * 8]     = ((const float4*)krow)[sg*2];
            *(float4*)&sk[r * SK_LD + sg * 8 + 4] = ((const float4*)krow)[sg*2+1];
            #pragma unroll
            for (int p = 0; p < 4; ++p)
                *(float4*)&sv[r * SV_LD + sg * 16 + p * 4] =
                    ((const float4*)vrow)[sg * 4 + p];
        }
        __syncthreads();

        // scores for this quarter's 16 kv columns (float4 broadcast reads)
        float s[16];
        float mt = MASKVAL;
        #pragma unroll
        for (int jj = 0; jj < 16; ++jj) {
            const int j = quarter * 16 + jj;
            const float4* kr = (const float4*)&sk[j * SK_LD];
            float acc = 0.f;
            #pragma unroll
            for (int r4 = 0; r4 < 8; ++r4) {
                float4 kv = kr[r4];
                acc = fmaf(q[r4*4+0], kv.x, acc);
                acc = fmaf(q[r4*4+1], kv.y, acc);
                acc = fmaf(q[r4*4+2], kv.z, acc);
                acc = fmaf(q[r4*4+3], kv.w, acc);
            }
            acc *= scale;
            const int gj = jt * 64 + j;
            acc = (gj <= t) ? acc : MASKVAL;
            s[jj] = acc;
            mt = fmaxf(mt, acc);
        }
        const float mnew = fmaxf(mrun, mt);
        const float alpha = expf(mrun - mnew);
        float psum = 0.f;
        #pragma unroll
        for (int jj = 0; jj < 16; ++jj) {
            float p = expf(s[jj] - mnew);
            s[jj] = p;
            psum += p;
        }
        lrun = lrun * alpha + psum;
        #pragma unroll
        for (int d = 0; d < 64; ++d) o[d] *= alpha;
        #pragma unroll
        for (int jj = 0; jj < 16; ++jj) {
            const int j = quarter * 16 + jj;
            const float p = s[jj];
            const float4* vr = (const float4*)&sv[j * SV_LD];
            #pragma unroll
            for (int d4 = 0; d4 < 16; ++d4) {
                float4 vv = vr[d4];
                o[d4*4+0] = fmaf(p, vv.x, o[d4*4+0]);
                o[d4*4+1] = fmaf(p, vv.y, o[d4*4+1]);
                o[d4*4+2] = fmaf(p, vv.z, o[d4*4+2]);
                o[d4*4+3] = fmaf(p, vv.w, o[d4*4+3]);
            }
        }
        mrun = mnew;
        __syncthreads();
    }

    // combine the 4 quarter-partials of each row
    sml[0][quarter][row] = mrun;
    sml[1][quarter][row] = lrun;
    __syncthreads();
    float mg = MASKVAL;
    #pragma unroll
    for (int qq = 0; qq < 4; ++qq) mg = fmaxf(mg, sml[0][qq][row]);
    float lg = 0.f;
    #pragma unroll
    for (int qq = 0; qq < 4; ++qq)
        lg += sml[1][qq][row] * expf(sml[0][qq][row] - mg);
    const float alpha = expf(mrun - mg);   // 0 for never-valid quarters

    // wave-serialized combine: `quarter == st` is wave-uniform; every o[]
    // access is a LITERAL index so o[] stays in VGPRs (the whole point).
    #pragma unroll
    for (int st = 0; st < 4; ++st) {
        if (quarter == st) {
            if (st == 0) {
                #pragma unroll
                for (int dd = 0; dd < 64; ++dd)
                    accum[row * 65 + dd] = alpha * o[dd];
            } else {
                #pragma unroll
                for (int dd = 0; dd < 64; ++dd)
                    accum[row * 65 + dd] += alpha * o[dd];
            }
        }
        __syncthreads();
    }

    // write output: thread (row, quarter) writes 16 contiguous floats
    {
        const float inv = 1.f / lg;
        float* orow = O + (size_t)(b * SEQ + t) * D_MODEL + h * D_HEAD;
        #pragma unroll
        for (int dd = 0; dd < 16; ++dd)
            orow[quarter * 16 + dd] =
                accum[row * 65 + quarter * 16 + dd] * inv;
    }
}

// ---------------------------------------------------------------------------
extern "C" void kernel_launch(void* const* d_in, const int* in_sizes, int n_in,
                              void* d_out, int out_size, void* d_ws, size_t ws_size,
                              hipStream_t stream)
{
    const float* x      = (const float*)d_in[0];
    const float* Wq     = (const float*)d_in[1];
    const float* bq     = (const float*)d_in[2];
    const float* Wk     = (const float*)d_in[3];
    const float* bk     = (const float*)d_in[4];
    const float* Wv     = (const float*)d_in[5];
    const float* bv     = (const float*)d_in[6];
    const float* Wo     = (const float*)d_in[7];
    const float* bo     = (const float*)d_in[8];
    const float* Wq_lsr = (const float*)d_in[9];
    const float* Wk_lsr = (const float*)d_in[10];
    float* out = (float*)d_out;

    float* ws      = (float*)d_ws;
    float* Wq_eff  = ws;                               // 1024*512
    float* Wk_eff  = Wq_eff + 1024 * 512;              // 1024*512
    float* bq_eff  = Wk_eff + 1024 * 512;              // 512
    float* bk_eff  = bq_eff + 512;                     // 512
    float* Ycat    = bk_eff + 512;                     // 4096*2048
    float* Oacc    = Ycat + (size_t)M_TOT * NCAT;      // 4096*1024

    eff_weight_kernel<<<2048, 256, 0, stream>>>(Wq, Wq_lsr, Wq_eff);
    eff_weight_kernel<<<2048, 256, 0, stream>>>(Wk, Wk_lsr, Wk_eff);
    eff_bias_kernel<<<1, 512, 0, stream>>>(bq, Wq_lsr, bq_eff);
    eff_bias_kernel<<<1, 512, 0, stream>>>(bk, Wk_lsr, bk_eff);

    proj_kernel<<<dim3(NCAT / 128, M_TOT / 64), 256, 0, stream>>>(
        x, Wq_eff, Wk_eff, Wv, bq_eff, bk_eff, bv, Ycat);

    flash_kernel<<<dim3(BATCH * N_HEADS, 32), 256, 0, stream>>>(Ycat, Oacc);

    out_kernel<<<dim3(D_MODEL / 128, M_TOT / 64), 256, 0, stream>>>(
        Oacc, Wo, bo, out);
}